// Round 1
// baseline (245.593 us; speedup 1.0000x reference)
//
#include <hip/hip_runtime.h>
#include <hip/hip_bf16.h>

#define BSZ   4
#define LSEQ  1024
#define NH    12
#define DDIM  768
#define NEN   42
#define NM    96
#define NPAIR (NEN*NEN)   /* 1764 */
#define OFF   1

// ---------------- workspace layout (floats) ----------------
// e_emb : BSZ*NEN*DDIM            = 129024
// e_att : BSZ*NEN*NH*LSEQ         = 2064384
// invS  : BSZ*NPAIR               = 7056
// ptil  : BSZ*NPAIR*LSEQ bf16     (after float section, 16B aligned)
#define EMB_CNT  (BSZ*NEN*DDIM)
#define EATT_CNT (BSZ*NEN*NH*LSEQ)
#define INVS_CNT (BSZ*NPAIR)
#define FLOAT_CNT (EMB_CNT + EATT_CNT + INVS_CNT)

// ---------------- kernel 1: entity embeddings (segment logsumexp) -------------
__global__ void ent_emb_kernel(const float* __restrict__ seq,
                               const int* __restrict__ mpos,
                               const int* __restrict__ ment,
                               float* __restrict__ e_emb) {
    int b = blockIdx.x / NEN, e = blockIdx.x % NEN;
    __shared__ int sp[NM];
    __shared__ int se[NM];
    int t = threadIdx.x;
    if (t < NM) { sp[t] = mpos[b*NM + t] + OFF; se[t] = ment[b*NM + t]; }
    __syncthreads();
    const float* sq = seq + (size_t)b * LSEQ * DDIM;
    for (int d = t; d < DDIM; d += blockDim.x) {
        float mx = -1e30f; int cnt = 0;
        for (int m = 0; m < NM; ++m)
            if (se[m] == e) { ++cnt; mx = fmaxf(mx, sq[(size_t)sp[m]*DDIM + d]); }
        float out = 0.f;
        if (cnt) {
            float s = 0.f;
            for (int m = 0; m < NM; ++m)
                if (se[m] == e) s += expf(sq[(size_t)sp[m]*DDIM + d] - mx);
            out = logf(fmaxf(s, 1e-30f)) + mx;
        }
        e_emb[((size_t)b*NEN + e)*DDIM + d] = out;
    }
}

// ---------------- kernel 2: entity attentions (segment mean) ------------------
__global__ void ent_att_kernel(const float* __restrict__ att,
                               const int* __restrict__ mpos,
                               const int* __restrict__ ment,
                               float* __restrict__ e_att) {
    int id = blockIdx.x;
    int h = id % NH;
    int e = (id / NH) % NEN;
    int b = id / (NH * NEN);
    __shared__ int sp[NM];
    __shared__ int se[NM];
    int t = threadIdx.x;
    if (t < NM) { sp[t] = mpos[b*NM + t] + OFF; se[t] = ment[b*NM + t]; }
    __syncthreads();
    const float* ab = att + ((size_t)(b*NH + h)) * LSEQ * LSEQ;
    float4 acc = {0.f, 0.f, 0.f, 0.f};
    int cnt = 0;
    for (int m = 0; m < NM; ++m) {
        if (se[m] == e) {
            ++cnt;
            float4 v = ((const float4*)(ab + (size_t)sp[m]*LSEQ))[t];
            acc.x += v.x; acc.y += v.y; acc.z += v.z; acc.w += v.w;
        }
    }
    float inv = cnt ? 1.f / (float)cnt : 0.f;
    acc.x *= inv; acc.y *= inv; acc.z *= inv; acc.w *= inv;
    ((float4*)(e_att + ((size_t)(b*NEN + e)*NH + h)*LSEQ))[t] = acc;
}

// ---------------- kernel 3: pair products p~ (bf16) + 1/denominator ----------
__global__ void pair_kernel(const float* __restrict__ e_att,
                            __hip_bfloat16* __restrict__ ptil,
                            float* __restrict__ invS) {
    int id = blockIdx.x;
    int pe = id % NPAIR;
    int b  = id / NPAIR;
    int a  = pe / NEN;
    int e  = pe % NEN;
    int t  = threadIdx.x;                    // 256 threads, 4 l each (float4)
    const float4* ra = (const float4*)(e_att + ((size_t)(b*NEN + a)*NH)*LSEQ);
    const float4* rb = (const float4*)(e_att + ((size_t)(b*NEN + e)*NH)*LSEQ);
    float4 acc = {0.f, 0.f, 0.f, 0.f};
    #pragma unroll
    for (int h = 0; h < NH; ++h) {
        float4 x = ra[h*(LSEQ/4) + t];
        float4 y = rb[h*(LSEQ/4) + t];
        acc.x += x.x*y.x; acc.y += x.y*y.y; acc.z += x.z*y.z; acc.w += x.w*y.w;
    }
    union { ushort4 u4; __hip_bfloat16 h[4]; } pk;
    pk.h[0] = __float2bfloat16(acc.x);
    pk.h[1] = __float2bfloat16(acc.y);
    pk.h[2] = __float2bfloat16(acc.z);
    pk.h[3] = __float2bfloat16(acc.w);
    *(ushort4*)(ptil + ((size_t)(b*NPAIR + pe))*LSEQ + t*4) = pk.u4;

    // block reduction of sum_l p~  ->  invS = 1/(sum + H*1e-5)
    float s = acc.x + acc.y + acc.z + acc.w;
    #pragma unroll
    for (int o = 32; o > 0; o >>= 1) s += __shfl_down(s, o, 64);
    __shared__ float red[4];
    if ((t & 63) == 0) red[t >> 6] = s;
    __syncthreads();
    if (t == 0) {
        float tot = red[0] + red[1] + red[2] + red[3];
        invS[b*NPAIR + pe] = 1.f / (tot + (float)NH * 1e-5f);
    }
}

// ---------------- kernel 4: gather hss / tss ---------------------------------
__global__ void gather_ht_kernel(const float* __restrict__ e_emb,
                                 const int* __restrict__ hts,
                                 float* __restrict__ out_h,
                                 float* __restrict__ out_t) {
    int id = blockIdx.x;                 // b*NPAIR + p
    int b  = id / NPAIR;
    int hi = hts[id*2 + 0];
    int ti = hts[id*2 + 1];
    const float4* eh = (const float4*)(e_emb + ((size_t)(b*NEN + hi))*DDIM);
    const float4* et = (const float4*)(e_emb + ((size_t)(b*NEN + ti))*DDIM);
    float4* oh = (float4*)(out_h + (size_t)id*DDIM);
    float4* ot = (float4*)(out_t + (size_t)id*DDIM);
    int t = threadIdx.x;
    if (t < DDIM/4) { oh[t] = eh[t]; ot[t] = et[t]; }
}

// ---------------- kernel 5: fmap GEMM  C = (ptil @ seq) * invS ---------------
#define TM 64
#define TN 64
#define TK 32
__global__ __launch_bounds__(256) void fmap_gemm_kernel(
        const __hip_bfloat16* __restrict__ ptil,
        const float* __restrict__ seq,
        const float* __restrict__ invS,
        float* __restrict__ fmap) {
    int bx = blockIdx.x;                 // N tile (12)
    int by = blockIdx.y;                 // M tile (28)
    int b  = blockIdx.z;                 // doc
    __shared__ float As[TM][TK + 1];
    __shared__ float Bs[TK][TN];
    int t  = threadIdx.x;
    int tx = t & 15, ty = t >> 4;
    int r0 = by * TM, c0 = bx * TN;
    const __hip_bfloat16* A  = ptil + (size_t)b * NPAIR * LSEQ;
    const float*          Bm = seq  + (size_t)b * LSEQ * DDIM;
    float acc[4][4] = {{0.f}};
    int lar = t >> 2, lak = (t & 3) * 8;     // A: 8 bf16 per thread
    int lbr = t >> 3, lbc = (t & 7) * 8;     // B: 8 floats per thread
    for (int k0 = 0; k0 < LSEQ; k0 += TK) {
        int gr = r0 + lar;
        if (gr < NPAIR) {
            uint4 raw = *(const uint4*)(A + (size_t)gr*LSEQ + k0 + lak);
            const __hip_bfloat16* hp = (const __hip_bfloat16*)&raw;
            #pragma unroll
            for (int i = 0; i < 8; ++i) As[lar][lak + i] = __bfloat162float(hp[i]);
        } else {
            #pragma unroll
            for (int i = 0; i < 8; ++i) As[lar][lak + i] = 0.f;
        }
        {
            const float4* src = (const float4*)(Bm + (size_t)(k0 + lbr)*DDIM + c0 + lbc);
            *(float4*)&Bs[lbr][lbc]     = src[0];
            *(float4*)&Bs[lbr][lbc + 4] = src[1];
        }
        __syncthreads();
        #pragma unroll
        for (int k = 0; k < TK; ++k) {
            float av[4];
            #pragma unroll
            for (int i = 0; i < 4; ++i) av[i] = As[ty*4 + i][k];
            float4 bv = *(const float4*)&Bs[k][tx*4];
            float bj[4] = {bv.x, bv.y, bv.z, bv.w};
            #pragma unroll
            for (int i = 0; i < 4; ++i)
                #pragma unroll
                for (int j = 0; j < 4; ++j)
                    acc[i][j] += av[i] * bj[j];
        }
        __syncthreads();
    }
    #pragma unroll
    for (int i = 0; i < 4; ++i) {
        int r = r0 + ty*4 + i;
        if (r < NPAIR) {
            float sc = invS[b*NPAIR + r];
            float4 o;
            o.x = acc[i][0]*sc; o.y = acc[i][1]*sc; o.z = acc[i][2]*sc; o.w = acc[i][3]*sc;
            *(float4*)(fmap + ((size_t)b*NPAIR + r)*DDIM + c0 + tx*4) = o;
        }
    }
}

// ---------------- launcher ---------------------------------------------------
extern "C" void kernel_launch(void* const* d_in, const int* in_sizes, int n_in,
                              void* d_out, int out_size, void* d_ws, size_t ws_size,
                              hipStream_t stream) {
    const float* seq  = (const float*)d_in[0];
    const float* att  = (const float*)d_in[1];
    const int*   mpos = (const int*)d_in[2];
    const int*   ment = (const int*)d_in[3];
    const int*   hts  = (const int*)d_in[4];

    float* ws_f  = (float*)d_ws;
    float* e_emb = ws_f;
    float* e_att = ws_f + EMB_CNT;
    float* invS  = ws_f + EMB_CNT + EATT_CNT;
    __hip_bfloat16* ptil = (__hip_bfloat16*)(ws_f + FLOAT_CNT);

    float* out_h = (float*)d_out;
    float* out_t = out_h + (size_t)BSZ*NPAIR*DDIM;
    float* fmap  = out_t + (size_t)BSZ*NPAIR*DDIM;

    hipLaunchKernelGGL(ent_emb_kernel, dim3(BSZ*NEN), dim3(256), 0, stream,
                       seq, mpos, ment, e_emb);
    hipLaunchKernelGGL(ent_att_kernel, dim3(BSZ*NEN*NH), dim3(256), 0, stream,
                       att, mpos, ment, e_att);
    hipLaunchKernelGGL(pair_kernel, dim3(BSZ*NPAIR), dim3(256), 0, stream,
                       e_att, ptil, invS);
    hipLaunchKernelGGL(gather_ht_kernel, dim3(BSZ*NPAIR), dim3(256), 0, stream,
                       e_emb, hts, out_h, out_t);
    hipLaunchKernelGGL(fmap_gemm_kernel, dim3(DDIM/TN, (NPAIR + TM - 1)/TM, BSZ),
                       dim3(256), 0, stream, ptil, seq, invS, fmap);
}

// Round 2
// 131.445 us; speedup vs baseline: 1.8684x; 1.8684x over previous
//
#include <hip/hip_runtime.h>
#include <hip/hip_bf16.h>

#define BSZ   4
#define LSEQ  1024
#define NH    12
#define DDIM  768
#define NEN   42
#define NM    96
#define NPAIR (NEN*NEN)   /* 1764 */
#define OFF   1

typedef short bf16x8 __attribute__((ext_vector_type(8)));
typedef float f32x4  __attribute__((ext_vector_type(4)));

// ---------------- workspace layout ----------------
// floats: e_emb | e_att | invS      then bf16: ptil | seqT
#define EMB_CNT  (BSZ*NEN*DDIM)
#define EATT_CNT (BSZ*NEN*NH*LSEQ)
#define INVS_CNT (BSZ*NPAIR)
#define FLOAT_CNT (EMB_CNT + EATT_CNT + INVS_CNT)
#define PTIL_CNT ((size_t)BSZ*NPAIR*LSEQ)

// ---------------- kernel 1: entity embeddings (segment logsumexp) -------------
__global__ void ent_emb_kernel(const float* __restrict__ seq,
                               const int* __restrict__ mpos,
                               const int* __restrict__ ment,
                               float* __restrict__ e_emb) {
    int b = blockIdx.x / NEN, e = blockIdx.x % NEN;
    __shared__ int sp[NM];
    __shared__ int se[NM];
    int t = threadIdx.x;
    if (t < NM) { sp[t] = mpos[b*NM + t] + OFF; se[t] = ment[b*NM + t]; }
    __syncthreads();
    const float* sq = seq + (size_t)b * LSEQ * DDIM;
    for (int d = t; d < DDIM; d += blockDim.x) {
        float mx = -1e30f; int cnt = 0;
        for (int m = 0; m < NM; ++m)
            if (se[m] == e) { ++cnt; mx = fmaxf(mx, sq[(size_t)sp[m]*DDIM + d]); }
        float out = 0.f;
        if (cnt) {
            float s = 0.f;
            for (int m = 0; m < NM; ++m)
                if (se[m] == e) s += expf(sq[(size_t)sp[m]*DDIM + d] - mx);
            out = logf(fmaxf(s, 1e-30f)) + mx;
        }
        e_emb[((size_t)b*NEN + e)*DDIM + d] = out;
    }
}

// ---------------- kernel 2: entity attentions (segment mean) ------------------
__global__ void ent_att_kernel(const float* __restrict__ att,
                               const int* __restrict__ mpos,
                               const int* __restrict__ ment,
                               float* __restrict__ e_att) {
    int id = blockIdx.x;
    int h = id % NH;
    int e = (id / NH) % NEN;
    int b = id / (NH * NEN);
    __shared__ int sp[NM];
    __shared__ int se[NM];
    int t = threadIdx.x;
    if (t < NM) { sp[t] = mpos[b*NM + t] + OFF; se[t] = ment[b*NM + t]; }
    __syncthreads();
    const float* ab = att + ((size_t)(b*NH + h)) * LSEQ * LSEQ;
    float4 acc = {0.f, 0.f, 0.f, 0.f};
    int cnt = 0;
    for (int m = 0; m < NM; ++m) {
        if (se[m] == e) {
            ++cnt;
            float4 v = ((const float4*)(ab + (size_t)sp[m]*LSEQ))[t];
            acc.x += v.x; acc.y += v.y; acc.z += v.z; acc.w += v.w;
        }
    }
    float inv = cnt ? 1.f / (float)cnt : 0.f;
    acc.x *= inv; acc.y *= inv; acc.z *= inv; acc.w *= inv;
    ((float4*)(e_att + ((size_t)(b*NEN + e)*NH + h)*LSEQ))[t] = acc;
}

// ---------------- kernel 3: pair products p~ (bf16) + 1/denominator ----------
__global__ void pair_kernel(const float* __restrict__ e_att,
                            __hip_bfloat16* __restrict__ ptil,
                            float* __restrict__ invS) {
    int id = blockIdx.x;
    int pe = id % NPAIR;
    int b  = id / NPAIR;
    int a  = pe / NEN;
    int e  = pe % NEN;
    int t  = threadIdx.x;                    // 256 threads, 4 l each (float4)
    const float4* ra = (const float4*)(e_att + ((size_t)(b*NEN + a)*NH)*LSEQ);
    const float4* rb = (const float4*)(e_att + ((size_t)(b*NEN + e)*NH)*LSEQ);
    float4 acc = {0.f, 0.f, 0.f, 0.f};
    #pragma unroll
    for (int h = 0; h < NH; ++h) {
        float4 x = ra[h*(LSEQ/4) + t];
        float4 y = rb[h*(LSEQ/4) + t];
        acc.x += x.x*y.x; acc.y += x.y*y.y; acc.z += x.z*y.z; acc.w += x.w*y.w;
    }
    union { ushort4 u4; __hip_bfloat16 h[4]; } pk;
    pk.h[0] = __float2bfloat16(acc.x);
    pk.h[1] = __float2bfloat16(acc.y);
    pk.h[2] = __float2bfloat16(acc.z);
    pk.h[3] = __float2bfloat16(acc.w);
    *(ushort4*)(ptil + ((size_t)(b*NPAIR + pe))*LSEQ + t*4) = pk.u4;

    // block reduction of sum_l p~  ->  invS = 1/(sum + H*1e-5)
    float s = acc.x + acc.y + acc.z + acc.w;
    #pragma unroll
    for (int o = 32; o > 0; o >>= 1) s += __shfl_down(s, o, 64);
    __shared__ float red[4];
    if ((t & 63) == 0) red[t >> 6] = s;
    __syncthreads();
    if (t == 0) {
        float tot = red[0] + red[1] + red[2] + red[3];
        invS[b*NPAIR + pe] = 1.f / (tot + (float)NH * 1e-5f);
    }
}

// ---------------- kernel 4: gather hss / tss ---------------------------------
__global__ void gather_ht_kernel(const float* __restrict__ e_emb,
                                 const int* __restrict__ hts,
                                 float* __restrict__ out_h,
                                 float* __restrict__ out_t) {
    int id = blockIdx.x;                 // b*NPAIR + p
    int b  = id / NPAIR;
    int hi = hts[id*2 + 0];
    int ti = hts[id*2 + 1];
    const float4* eh = (const float4*)(e_emb + ((size_t)(b*NEN + hi))*DDIM);
    const float4* et = (const float4*)(e_emb + ((size_t)(b*NEN + ti))*DDIM);
    float4* oh = (float4*)(out_h + (size_t)id*DDIM);
    float4* ot = (float4*)(out_t + (size_t)id*DDIM);
    int t = threadIdx.x;
    if (t < DDIM/4) { oh[t] = eh[t]; ot[t] = et[t]; }
}

// ---------------- kernel 5: seq f32 [L][D] -> seqT bf16 [D][L] ---------------
__global__ void seq2bf16T_kernel(const float* __restrict__ seq,
                                 __hip_bfloat16* __restrict__ seqT) {
    int b  = blockIdx.z;
    int l0 = blockIdx.x * 32;
    int d0 = blockIdx.y * 32;
    __shared__ float tile[32][33];
    int t = threadIdx.x;
    int l = t >> 3, dq = (t & 7) * 4;
    float4 v = *(const float4*)(seq + ((size_t)b*LSEQ + l0 + l)*DDIM + d0 + dq);
    tile[l][dq+0] = v.x; tile[l][dq+1] = v.y; tile[l][dq+2] = v.z; tile[l][dq+3] = v.w;
    __syncthreads();
    int d = t >> 3, lq = (t & 7) * 4;
    union { ushort4 u4; __hip_bfloat16 h[4]; } pk;
    pk.h[0] = __float2bfloat16(tile[lq+0][d]);
    pk.h[1] = __float2bfloat16(tile[lq+1][d]);
    pk.h[2] = __float2bfloat16(tile[lq+2][d]);
    pk.h[3] = __float2bfloat16(tile[lq+3][d]);
    *(ushort4*)(seqT + ((size_t)b*DDIM + d0 + d)*LSEQ + l0 + lq) = pk.u4;
}

// ---------------- kernel 6: fmap GEMM (MFMA bf16)  C = (ptil @ seq) * invS ---
#define BM 128
#define BN 64
#define BK 64
#define MT 14           /* ceil(1764/128) */
#define NT (DDIM/BN)    /* 12 */

__global__ __launch_bounds__(256) void fmap_mfma_kernel(
        const __hip_bfloat16* __restrict__ ptil,
        const __hip_bfloat16* __restrict__ seqT,
        const float* __restrict__ invS,
        float* __restrict__ fmap) {
    __shared__ __hip_bfloat16 As[BM][BK + 8];   // 128 x 72  (padded: conflict-free)
    __shared__ __hip_bfloat16 Bs[BN][BK + 8];   // 64 x 72   (col-major tile: Bs[col][k])

    const int t    = threadIdx.x;
    const int lane = t & 63;
    const int wid  = t >> 6;
    const int wr   = wid >> 1;      // 0..1 : 64-row half
    const int wc   = wid & 1;       // 0..1 : 32-col half
    const int bx = blockIdx.x, by = blockIdx.y, b = blockIdx.z;
    const int r0 = bx * BM, c0 = by * BN;

    const __hip_bfloat16* A  = ptil + (size_t)b * NPAIR * LSEQ;
    const __hip_bfloat16* Bt = seqT + (size_t)b * DDIM * LSEQ;

    // staging indices
    const int ar = t >> 1;            // A row 0..127
    const int ae = (t & 1) * 32;      // A elem offset (covers 32 elems = 64B)
    const int bc = t >> 2;            // B col 0..63
    const int bq = (t & 3) * 16;      // B elem offset (covers 16 elems = 32B)

    const f32x4 zero = {0.f, 0.f, 0.f, 0.f};
    f32x4 acc[4][2];
    #pragma unroll
    for (int m = 0; m < 4; ++m)
        #pragma unroll
        for (int n = 0; n < 2; ++n) acc[m][n] = zero;

    const int fr = lane & 15, kg = lane >> 4;

    for (int k0 = 0; k0 < LSEQ; k0 += BK) {
        // ---- stage A (128 x 64 bf16) ----
        int gr = r0 + ar;
        if (gr < NPAIR) {
            const __hip_bfloat16* src = A + (size_t)gr * LSEQ + k0 + ae;
            uint4 r0v = *(const uint4*)(src +  0);
            uint4 r1v = *(const uint4*)(src +  8);
            uint4 r2v = *(const uint4*)(src + 16);
            uint4 r3v = *(const uint4*)(src + 24);
            *(uint4*)(&As[ar][ae +  0]) = r0v;
            *(uint4*)(&As[ar][ae +  8]) = r1v;
            *(uint4*)(&As[ar][ae + 16]) = r2v;
            *(uint4*)(&As[ar][ae + 24]) = r3v;
        } else {
            uint4 z = {0u, 0u, 0u, 0u};
            *(uint4*)(&As[ar][ae +  0]) = z;
            *(uint4*)(&As[ar][ae +  8]) = z;
            *(uint4*)(&As[ar][ae + 16]) = z;
            *(uint4*)(&As[ar][ae + 24]) = z;
        }
        // ---- stage B^T (64 cols x 64 k) ----
        {
            const __hip_bfloat16* src = Bt + (size_t)(c0 + bc) * LSEQ + k0 + bq;
            uint4 b0v = *(const uint4*)(src + 0);
            uint4 b1v = *(const uint4*)(src + 8);
            *(uint4*)(&Bs[bc][bq + 0]) = b0v;
            *(uint4*)(&Bs[bc][bq + 8]) = b1v;
        }
        __syncthreads();

        // ---- MFMA: 2 K-chunks of 32, 4x2 fragments ----
        #pragma unroll
        for (int ks = 0; ks < 2; ++ks) {
            bf16x8 af[4], bfv[2];
            #pragma unroll
            for (int m = 0; m < 4; ++m)
                af[m] = *(const bf16x8*)(&As[wr*64 + m*16 + fr][ks*32 + kg*8]);
            #pragma unroll
            for (int n = 0; n < 2; ++n)
                bfv[n] = *(const bf16x8*)(&Bs[wc*32 + n*16 + fr][ks*32 + kg*8]);
            #pragma unroll
            for (int m = 0; m < 4; ++m)
                #pragma unroll
                for (int n = 0; n < 2; ++n)
                    acc[m][n] = __builtin_amdgcn_mfma_f32_16x16x32_bf16(
                                    af[m], bfv[n], acc[m][n], 0, 0, 0);
        }
        __syncthreads();
    }

    // ---- epilogue: scale by invS[row], store ----
    #pragma unroll
    for (int m = 0; m < 4; ++m) {
        int rb = r0 + wr*64 + m*16 + kg*4;
        #pragma unroll
        for (int n = 0; n < 2; ++n) {
            int col = c0 + wc*32 + n*16 + fr;
            #pragma unroll
            for (int i = 0; i < 4; ++i) {
                int row = rb + i;
                if (row < NPAIR) {
                    float sc = invS[b*NPAIR + row];
                    fmap[((size_t)b*NPAIR + row)*DDIM + col] = acc[m][n][i] * sc;
                }
            }
        }
    }
}

// ---------------- launcher ---------------------------------------------------
extern "C" void kernel_launch(void* const* d_in, const int* in_sizes, int n_in,
                              void* d_out, int out_size, void* d_ws, size_t ws_size,
                              hipStream_t stream) {
    const float* seq  = (const float*)d_in[0];
    const float* att  = (const float*)d_in[1];
    const int*   mpos = (const int*)d_in[2];
    const int*   ment = (const int*)d_in[3];
    const int*   hts  = (const int*)d_in[4];

    float* ws_f  = (float*)d_ws;
    float* e_emb = ws_f;
    float* e_att = ws_f + EMB_CNT;
    float* invS  = ws_f + EMB_CNT + EATT_CNT;
    __hip_bfloat16* ptil = (__hip_bfloat16*)(ws_f + FLOAT_CNT);
    __hip_bfloat16* seqT = ptil + PTIL_CNT;

    float* out_h = (float*)d_out;
    float* out_t = out_h + (size_t)BSZ*NPAIR*DDIM;
    float* fmap  = out_t + (size_t)BSZ*NPAIR*DDIM;

    hipLaunchKernelGGL(ent_emb_kernel, dim3(BSZ*NEN), dim3(256), 0, stream,
                       seq, mpos, ment, e_emb);
    hipLaunchKernelGGL(ent_att_kernel, dim3(BSZ*NEN*NH), dim3(256), 0, stream,
                       att, mpos, ment, e_att);
    hipLaunchKernelGGL(pair_kernel, dim3(BSZ*NPAIR), dim3(256), 0, stream,
                       e_att, ptil, invS);
    hipLaunchKernelGGL(gather_ht_kernel, dim3(BSZ*NPAIR), dim3(256), 0, stream,
                       e_emb, hts, out_h, out_t);
    hipLaunchKernelGGL(seq2bf16T_kernel, dim3(LSEQ/32, DDIM/32, BSZ),
                       dim3(256), 0, stream, seq, seqT);
    hipLaunchKernelGGL(fmap_mfma_kernel, dim3(MT, NT, BSZ),
                       dim3(256), 0, stream, ptil, seqT, invS, fmap);
}